// Round 1
// baseline (25086.649 us; speedup 1.0000x reference)
//
#include <hip/hip_runtime.h>
#include <hip/hip_bf16.h>
#include <math.h>

// Decoder with attention: V=32000 E=512 H=1024 B=64 S=128 T=65 (NT=64 steps)
#define BATCH 64
#define SRC   128
#define HID   1024
#define EMB   512
#define NT    64
#define KIH   1536   // E+H
#define G4    4096   // 4H
#define D2    2048   // 2H
#define K3    3072   // 3H

__device__ __forceinline__ float sigmoidf_(float x){ return 1.0f/(1.0f+expf(-x)); }

// ---------------- generic C[m][n] = sum_k A[m][k]*W[n][k] (+bias1[n]+bias2[n]) ----------------
// BM=BN=64, BK=16, 256 threads, 4x4 micro-tile. M,N multiples of 64; K multiple of 16.
__global__ void gemm_nt_kernel(const float* __restrict__ A, const float* __restrict__ W,
                               float* __restrict__ C, int M, int N, int K,
                               const float* __restrict__ bias1, const float* __restrict__ bias2){
  const int n0 = blockIdx.x * 64;
  const int m0 = blockIdx.y * 64;
  const int tid = threadIdx.x;
  const int tx = tid & 15, ty = tid >> 4;
  __shared__ float As[16][64];
  __shared__ float Bs[16][64];
  float acc[4][4] = {};
  const int row = tid >> 2, kc = (tid & 3) * 4;
  for (int k0 = 0; k0 < K; k0 += 16){
    float4 av = *(const float4*)(A + (size_t)(m0+row)*K + k0 + kc);
    float4 wv = *(const float4*)(W + (size_t)(n0+row)*K + k0 + kc);
    As[kc+0][row]=av.x; As[kc+1][row]=av.y; As[kc+2][row]=av.z; As[kc+3][row]=av.w;
    Bs[kc+0][row]=wv.x; Bs[kc+1][row]=wv.y; Bs[kc+2][row]=wv.z; Bs[kc+3][row]=wv.w;
    __syncthreads();
    #pragma unroll
    for (int k=0;k<16;++k){
      float4 a4 = *(const float4*)&As[k][ty*4];
      float4 b4 = *(const float4*)&Bs[k][tx*4];
      acc[0][0]+=a4.x*b4.x; acc[0][1]+=a4.x*b4.y; acc[0][2]+=a4.x*b4.z; acc[0][3]+=a4.x*b4.w;
      acc[1][0]+=a4.y*b4.x; acc[1][1]+=a4.y*b4.y; acc[1][2]+=a4.y*b4.z; acc[1][3]+=a4.y*b4.w;
      acc[2][0]+=a4.z*b4.x; acc[2][1]+=a4.z*b4.y; acc[2][2]+=a4.z*b4.z; acc[2][3]+=a4.z*b4.w;
      acc[3][0]+=a4.w*b4.x; acc[3][1]+=a4.w*b4.y; acc[3][2]+=a4.w*b4.z; acc[3][3]+=a4.w*b4.w;
    }
    __syncthreads();
  }
  float bias[4] = {0.f,0.f,0.f,0.f};
  if (bias1){ for (int j=0;j<4;++j) bias[j] += bias1[n0+tx*4+j]; }
  if (bias2){ for (int j=0;j<4;++j) bias[j] += bias2[n0+tx*4+j]; }
  for (int i=0;i<4;++i)
    for (int j=0;j<4;++j)
      C[(size_t)(m0+ty*4+i)*N + n0+tx*4+j] = acc[i][j] + bias[j];
}

// ---------------- gates[b][j] = [y_t | O_prev] . W_ih[j] + hh_term[b][j] ----------------
// BM=64 (all b), BN=32 cols, BK=16, 256 threads, micro 4(m)x2(n)
__global__ void gates_kernel(const int* __restrict__ tgt, int t,
                             const float* __restrict__ embedding,
                             const float* __restrict__ O_prev,
                             const float* __restrict__ W_ih,
                             const float* __restrict__ hh_term,
                             float* __restrict__ gates){
  const int j0 = blockIdx.x * 32;
  const int tid = threadIdx.x;
  const int tx = tid & 15;   // 2 cols each
  const int ty = tid >> 4;   // 4 rows each
  __shared__ float As[16][64];
  __shared__ float Bs[16][32];
  __shared__ int toks[64];
  if (tid < 64) toks[tid] = tgt[t*BATCH + tid];
  __syncthreads();
  float acc[4][2] = {};
  const int arow = tid >> 2, akc = (tid & 3) * 4;
  const int nr = tid >> 3,  wkc = (tid & 7) * 2;
  for (int k0 = 0; k0 < KIH; k0 += 16){
    // A tile 64x16: per-row gather from embedding or O_prev
    int col = k0 + akc;
    float4 av;
    if (col < EMB) av = *(const float4*)(embedding + (size_t)toks[arow]*EMB + col);
    else           av = *(const float4*)(O_prev + (size_t)arow*HID + (col - EMB));
    As[akc+0][arow]=av.x; As[akc+1][arow]=av.y; As[akc+2][arow]=av.z; As[akc+3][arow]=av.w;
    // W tile 32x16
    float2 wv = *(const float2*)(W_ih + (size_t)(j0+nr)*KIH + k0 + wkc);
    Bs[wkc+0][nr]=wv.x; Bs[wkc+1][nr]=wv.y;
    __syncthreads();
    #pragma unroll
    for (int k=0;k<16;++k){
      float4 a4 = *(const float4*)&As[k][ty*4];
      float2 b2 = *(const float2*)&Bs[k][tx*2];
      acc[0][0]+=a4.x*b2.x; acc[0][1]+=a4.x*b2.y;
      acc[1][0]+=a4.y*b2.x; acc[1][1]+=a4.y*b2.y;
      acc[2][0]+=a4.z*b2.x; acc[2][1]+=a4.z*b2.y;
      acc[3][0]+=a4.w*b2.x; acc[3][1]+=a4.w*b2.y;
    }
    __syncthreads();
  }
  for (int i=0;i<4;++i){
    int m = ty*4+i;
    for (int j=0;j<2;++j){
      int n = j0 + tx*2 + j;
      gates[m*G4 + n] = acc[i][j] + hh_term[m*G4 + n];
    }
  }
}

// ---------------- per-b: h from gates; e = enc_proj . h; softmax -> alpha ----------------
__global__ void attn1_kernel(const float* __restrict__ gates, const float* __restrict__ c0,
                             const float* __restrict__ enc_proj, const int* __restrict__ enc_mask,
                             float* __restrict__ h_out, float* __restrict__ alpha_out){
  const int b = blockIdx.x;
  const int tid = threadIdx.x;
  __shared__ float hs[HID];
  __shared__ float es[SRC];
  __shared__ float red[256];
  // h = sig(o)*tanh(sig(f)*c0 + sig(i)*tanh(g))
  for (int j = tid; j < HID; j += 256){
    float gi = gates[b*G4 + j];
    float gf = gates[b*G4 + HID + j];
    float gg = gates[b*G4 + 2*HID + j];
    float go = gates[b*G4 + 3*HID + j];
    float c = sigmoidf_(gf)*c0[b*HID + j] + sigmoidf_(gi)*tanhf(gg);
    float h = sigmoidf_(go)*tanhf(c);
    hs[j] = h;
    h_out[b*HID + j] = h;
  }
  __syncthreads();
  // e[s] = enc_proj[b][s][:] . h ; one wave per s
  const int wave = tid >> 6, lane = tid & 63;
  for (int s = wave; s < SRC; s += 4){
    const float* ep = enc_proj + ((size_t)b*SRC + s)*HID;
    float sum = 0.f;
    #pragma unroll 4
    for (int k = lane; k < HID; k += 64) sum += ep[k]*hs[k];
    for (int off = 32; off; off >>= 1) sum += __shfl_down(sum, off);
    if (lane == 0) es[s] = sum;
  }
  __syncthreads();
  // masked softmax over s (block-wide tree reduce)
  float v = -INFINITY;
  if (tid < SRC){
    v = es[tid];
    if (enc_mask[b*SRC + tid] != 0) v = -INFINITY;
  }
  red[tid] = v; __syncthreads();
  for (int off = 128; off; off >>= 1){ if (tid < off) red[tid] = fmaxf(red[tid], red[tid+off]); __syncthreads(); }
  float m = red[0]; __syncthreads();
  float p = (tid < SRC) ? expf(v - m) : 0.f;
  red[tid] = p; __syncthreads();
  for (int off = 128; off; off >>= 1){ if (tid < off) red[tid] += red[tid+off]; __syncthreads(); }
  float ssum = red[0];
  if (tid < SRC) alpha_out[b*SRC + tid] = p / ssum;
}

// ---------------- a[b][d] = sum_s alpha[b][s] * enc_hidden[b][s][d] ----------------
// 4 blocks per b, 512 d each
__global__ void attn2_kernel(const float* __restrict__ alpha, const float* __restrict__ enc_hidden,
                             float* __restrict__ a_out){
  const int b = blockIdx.x >> 2;
  const int dchunk = blockIdx.x & 3;
  const int tid = threadIdx.x;
  __shared__ float als[SRC];
  if (tid < SRC) als[tid] = alpha[b*SRC + tid];
  __syncthreads();
  const int d0 = dchunk*512;
  for (int d = d0 + tid; d < d0 + 512; d += 256){
    const float* eh = enc_hidden + (size_t)b*SRC*D2 + d;
    float acc = 0.f;
    #pragma unroll 8
    for (int s = 0; s < SRC; ++s) acc += als[s]*eh[(size_t)s*D2];
    a_out[b*D2 + d] = acc;
  }
}

// ---------------- O[b][j] = tanh([h|a][b] . W_comb[j]) ; write O_buf and outs[t] ----------------
// BM=64, BN=16, BK=16, 256 threads, micro 4(m)x1(n)
__global__ void comb_kernel(const float* __restrict__ h, const float* __restrict__ a,
                            const float* __restrict__ W_comb,
                            float* __restrict__ O_buf, float* __restrict__ out, int t){
  const int j0 = blockIdx.x * 16;
  const int tid = threadIdx.x;
  const int tx = tid & 15;   // 1 col
  const int ty = tid >> 4;   // 4 rows
  __shared__ float As[16][64];
  __shared__ float Bs[16][16];
  float acc[4] = {0.f,0.f,0.f,0.f};
  const int arow = tid >> 2, akc = (tid & 3)*4;
  const int nr = tid >> 4, wkc = tid & 15;
  for (int k0 = 0; k0 < K3; k0 += 16){
    int col = k0 + akc;
    float4 av;
    if (col < HID) av = *(const float4*)(h + (size_t)arow*HID + col);
    else           av = *(const float4*)(a + (size_t)arow*D2 + (col - HID));
    As[akc+0][arow]=av.x; As[akc+1][arow]=av.y; As[akc+2][arow]=av.z; As[akc+3][arow]=av.w;
    Bs[wkc][nr] = W_comb[(size_t)(j0+nr)*K3 + k0 + wkc];
    __syncthreads();
    #pragma unroll
    for (int k=0;k<16;++k){
      float4 a4 = *(const float4*)&As[k][ty*4];
      float b0 = Bs[k][tx];
      acc[0]+=a4.x*b0; acc[1]+=a4.y*b0; acc[2]+=a4.z*b0; acc[3]+=a4.w*b0;
    }
    __syncthreads();
  }
  for (int i=0;i<4;++i){
    int m = ty*4+i, n = j0+tx;
    float vv = tanhf(acc[i]);
    O_buf[m*HID + n] = vv;
    out[(size_t)t*BATCH*HID + m*HID + n] = vv;
  }
}

__global__ void zero_kernel(float* __restrict__ p, int n){
  int i = blockIdx.x*256 + threadIdx.x;
  if (i < n) p[i] = 0.f;
}

extern "C" void kernel_launch(void* const* d_in, const int* in_sizes, int n_in,
                              void* d_out, int out_size, void* d_ws, size_t ws_size,
                              hipStream_t stream) {
  const int*   tgt        = (const int*)d_in[0];
  const float* enc_hidden = (const float*)d_in[1];
  const int*   enc_mask   = (const int*)d_in[2];
  const float* dih        = (const float*)d_in[3];
  const float* dic        = (const float*)d_in[4];
  const float* emb        = (const float*)d_in[5];
  const float* W_ih       = (const float*)d_in[6];
  const float* W_hh       = (const float*)d_in[7];
  const float* b_ih       = (const float*)d_in[8];
  const float* b_hh       = (const float*)d_in[9];
  const float* W_att      = (const float*)d_in[10];
  const float* W_comb     = (const float*)d_in[11];
  float* out = (float*)d_out;

  float* ws       = (float*)d_ws;
  float* enc_proj = ws;                      // 8192*1024
  float* hh_term  = enc_proj + 8192*1024;    // 64*4096
  float* gates    = hh_term + BATCH*G4;      // 64*4096
  float* hbuf     = gates + BATCH*G4;        // 64*1024
  float* abuf     = hbuf + BATCH*HID;        // 64*2048
  float* alphab   = abuf + BATCH*D2;         // 64*128
  float* Obuf     = alphab + BATCH*SRC;      // 64*1024

  // precompute: enc_proj = enc_hidden @ W_att.T   (M=8192, N=1024, K=2048)
  gemm_nt_kernel<<<dim3(HID/64, (BATCH*SRC)/64), 256, 0, stream>>>(
      enc_hidden, W_att, enc_proj, BATCH*SRC, HID, D2, nullptr, nullptr);
  // precompute: hh_term = dih @ W_hh.T + b_ih + b_hh  (M=64, N=4096, K=1024)
  gemm_nt_kernel<<<dim3(G4/64, 1), 256, 0, stream>>>(
      dih, W_hh, hh_term, BATCH, G4, HID, b_ih, b_hh);
  // o0 = zeros
  zero_kernel<<<dim3((BATCH*HID)/256), 256, 0, stream>>>(Obuf, BATCH*HID);

  for (int t = 0; t < NT; ++t){
    gates_kernel<<<dim3(G4/32), 256, 0, stream>>>(tgt, t, emb, Obuf, W_ih, hh_term, gates);
    attn1_kernel<<<dim3(BATCH), 256, 0, stream>>>(gates, dic, enc_proj, enc_mask, hbuf, alphab);
    attn2_kernel<<<dim3(BATCH*4), 256, 0, stream>>>(alphab, enc_hidden, abuf);
    comb_kernel<<<dim3(HID/16), 256, 0, stream>>>(hbuf, abuf, W_comb, Obuf, out, t);
  }
}

// Round 2
// 5400.958 us; speedup vs baseline: 4.6449x; 4.6449x over previous
//
#include <hip/hip_runtime.h>
#include <hip/hip_bf16.h>
#include <math.h>

// Decoder with attention: V=32000 E=512 H=1024 B=64 S=128 T=65 (NT=64 steps)
#define BATCH 64
#define SRC   128
#define HID   1024
#define EMB   512
#define NT    64
#define G4    4096   // 4H

__device__ __forceinline__ float sigmoidf_(float x){ return 1.0f/(1.0f+expf(-x)); }

// ===================== skinny GEMM: partial[kc][m][n] = sum_k A[m][k]*W[n][k] =====================
// M=64 (batch), BN=128, BK=16, split-K via blockIdx.y. 256 threads = 4 waves.
// wave owns 64x32 sub-tile; lane grid 8(m-groups of 8) x 8(n-groups of 4); micro 8x4.
// AMODE 0: A[m][k] with leading dim lda.
// AMODE 1: k<512 -> emb[toks[m]][k], else A[m][k-512] (lda applies to A part).
template<int AMODE>
__launch_bounds__(256, 2)
__global__ void skinny_gemm(const float* __restrict__ A, int lda,
                            const int* __restrict__ toks, const float* __restrict__ emb,
                            const float* __restrict__ W, int ldw,
                            float* __restrict__ partial, int N, int Kchunk){
  const int nc = blockIdx.x;
  const int kc = blockIdx.y;
  const int kbase = kc * Kchunk;
  const int tid = threadIdx.x;
  __shared__ float As[16][64];
  __shared__ float Bs[16][128];
  const int wave = tid >> 6, lane = tid & 63;
  const int lm = lane & 7, ln = lane >> 3;
  const int nwave = nc*128 + wave*32;
  float acc[8][4] = {};
  const int arow = tid >> 2, akc = (tid & 3) * 4;
  for (int k0 = 0; k0 < Kchunk; k0 += 16){
    int kg = kbase + k0 + akc;
    float4 av;
    if (AMODE == 1){
      if (kg < EMB) av = *(const float4*)(emb + (size_t)toks[arow]*EMB + kg);
      else          av = *(const float4*)(A + (size_t)arow*lda + (kg - EMB));
    } else {
      av = *(const float4*)(A + (size_t)arow*lda + kg);
    }
    As[akc+0][arow]=av.x; As[akc+1][arow]=av.y; As[akc+2][arow]=av.z; As[akc+3][arow]=av.w;
    #pragma unroll
    for (int r = 0; r < 2; ++r){
      int idx = tid + r*256;
      int nrow = idx >> 2, bkc = (idx & 3) * 4;
      float4 wv = *(const float4*)(W + (size_t)(nc*128 + nrow)*ldw + kbase + k0 + bkc);
      Bs[bkc+0][nrow]=wv.x; Bs[bkc+1][nrow]=wv.y; Bs[bkc+2][nrow]=wv.z; Bs[bkc+3][nrow]=wv.w;
    }
    __syncthreads();
    #pragma unroll
    for (int k = 0; k < 16; ++k){
      float4 alo = *(const float4*)&As[k][lm*8];
      float4 ahi = *(const float4*)&As[k][lm*8+4];
      float4 b4  = *(const float4*)&Bs[k][wave*32 + ln*4];
      float am[8] = {alo.x,alo.y,alo.z,alo.w,ahi.x,ahi.y,ahi.z,ahi.w};
      float bn[4] = {b4.x,b4.y,b4.z,b4.w};
      #pragma unroll
      for (int i=0;i<8;++i)
        #pragma unroll
        for (int j=0;j<4;++j)
          acc[i][j] += am[i]*bn[j];
    }
    __syncthreads();
  }
  for (int i=0;i<8;++i){
    int m = lm*8+i;
    float4 v = make_float4(acc[i][0],acc[i][1],acc[i][2],acc[i][3]);
    *(float4*)(partial + ((size_t)(kc*64 + m))*N + nwave + ln*4) = v;
  }
}

// ===================== big GEMM: C[m][n] = sum_k A[m][k]*W[n][k] =====================
// BM=64 (blockIdx.y), BN=128 (blockIdx.x), full K loop. Same micro structure.
__launch_bounds__(256, 2)
__global__ void big_gemm(const float* __restrict__ A, int lda,
                         const float* __restrict__ W, int ldw,
                         float* __restrict__ C, int N, int K){
  const int nc = blockIdx.x;
  const int m0 = blockIdx.y * 64;
  const int tid = threadIdx.x;
  __shared__ float As[16][64];
  __shared__ float Bs[16][128];
  const int wave = tid >> 6, lane = tid & 63;
  const int lm = lane & 7, ln = lane >> 3;
  const int nwave = nc*128 + wave*32;
  float acc[8][4] = {};
  const int arow = tid >> 2, akc = (tid & 3) * 4;
  for (int k0 = 0; k0 < K; k0 += 16){
    float4 av = *(const float4*)(A + (size_t)(m0+arow)*lda + k0 + akc);
    As[akc+0][arow]=av.x; As[akc+1][arow]=av.y; As[akc+2][arow]=av.z; As[akc+3][arow]=av.w;
    #pragma unroll
    for (int r = 0; r < 2; ++r){
      int idx = tid + r*256;
      int nrow = idx >> 2, bkc = (idx & 3) * 4;
      float4 wv = *(const float4*)(W + (size_t)(nc*128 + nrow)*ldw + k0 + bkc);
      Bs[bkc+0][nrow]=wv.x; Bs[bkc+1][nrow]=wv.y; Bs[bkc+2][nrow]=wv.z; Bs[bkc+3][nrow]=wv.w;
    }
    __syncthreads();
    #pragma unroll
    for (int k = 0; k < 16; ++k){
      float4 alo = *(const float4*)&As[k][lm*8];
      float4 ahi = *(const float4*)&As[k][lm*8+4];
      float4 b4  = *(const float4*)&Bs[k][wave*32 + ln*4];
      float am[8] = {alo.x,alo.y,alo.z,alo.w,ahi.x,ahi.y,ahi.z,ahi.w};
      float bn[4] = {b4.x,b4.y,b4.z,b4.w};
      #pragma unroll
      for (int i=0;i<8;++i)
        #pragma unroll
        for (int j=0;j<4;++j)
          acc[i][j] += am[i]*bn[j];
    }
    __syncthreads();
  }
  for (int i=0;i<8;++i){
    int m = m0 + lm*8+i;
    float4 v = make_float4(acc[i][0],acc[i][1],acc[i][2],acc[i][3]);
    *(float4*)(C + (size_t)m*N + nwave + ln*4) = v;
  }
}

// ===================== hh_term = sum_kc partial + b_ih + b_hh =====================
__global__ void hh_reduce_kernel(const float* __restrict__ partial,
                                 const float* __restrict__ b_ih, const float* __restrict__ b_hh,
                                 float* __restrict__ hh_term){
  int g = blockIdx.x*512 + threadIdx.x;   // 64*4096
  int n = g & 4095;
  int b = g >> 12;
  float s = b_ih[n] + b_hh[n];
  #pragma unroll
  for (int kc=0; kc<8; ++kc) s += partial[((size_t)(kc*64+b))*G4 + n];
  hh_term[g] = s;
}

// ===================== h = LSTM nonlinearity from gate partials =====================
__global__ void h_kernel(const float* __restrict__ partial, const float* __restrict__ hh_term,
                         const float* __restrict__ c0, float* __restrict__ h){
  int g = blockIdx.x*256 + threadIdx.x;   // 64*1024
  int j = g & 1023;
  int b = g >> 10;
  float gate[4];
  #pragma unroll
  for (int q=0;q<4;++q){
    int n = q*HID + j;
    float s = hh_term[b*G4 + n];
    #pragma unroll
    for (int kc=0; kc<8; ++kc) s += partial[((size_t)(kc*64+b))*G4 + n];
    gate[q] = s;
  }
  float c = sigmoidf_(gate[1])*c0[g] + sigmoidf_(gate[0])*tanhf(gate[2]);
  h[g] = sigmoidf_(gate[3])*tanhf(c);
}

// ===================== e = enc_proj . h ; softmax ; comb_a = alpha . encW =====================
__launch_bounds__(512, 2)
__global__ void attn_kernel(const float* __restrict__ h, const float* __restrict__ enc_proj,
                            const float* __restrict__ encW, const int* __restrict__ enc_mask,
                            float* __restrict__ comb_a){
  const int b = blockIdx.x;
  const int tid = threadIdx.x;
  __shared__ float hs[HID];
  __shared__ float es[SRC];
  __shared__ float red[SRC];
  __shared__ float als[SRC];
  hs[tid] = h[b*HID + tid];
  hs[tid+512] = h[b*HID + 512 + tid];
  __syncthreads();
  const int wave = tid >> 6, lane = tid & 63;
  for (int s = wave*16; s < wave*16 + 16; ++s){
    const float* ep = enc_proj + ((size_t)b*SRC + s)*HID;
    float sum = 0.f;
    #pragma unroll
    for (int i=0;i<4;++i){
      float4 v  = *(const float4*)(ep + i*256 + lane*4);
      float4 hv = *(const float4*)&hs[i*256 + lane*4];
      sum += v.x*hv.x + v.y*hv.y + v.z*hv.z + v.w*hv.w;
    }
    #pragma unroll
    for (int off=32; off; off>>=1) sum += __shfl_down(sum, off);
    if (lane == 0) es[s] = sum;
  }
  __syncthreads();
  bool msk = false; float ev = 0.f;
  if (tid < SRC){
    ev = es[tid];
    msk = (enc_mask[b*SRC + tid] != 0);
    red[tid] = msk ? -1e30f : ev;
  }
  __syncthreads();
  for (int off=64; off>=1; off>>=1){ if (tid < off) red[tid] = fmaxf(red[tid], red[tid+off]); __syncthreads(); }
  float mval = red[0]; __syncthreads();
  float p = 0.f;
  if (tid < SRC && !msk) p = expf(ev - mval);
  if (tid < SRC) red[tid] = p;
  __syncthreads();
  for (int off=64; off>=1; off>>=1){ if (tid < off) red[tid] += red[tid+off]; __syncthreads(); }
  float ssum = red[0]; __syncthreads();
  if (tid < SRC) als[tid] = p / ssum;
  __syncthreads();
  // comb_a[b][n] = sum_s alpha[s] * encW[b][s][n]
  const float* ew = encW + (size_t)b*SRC*HID;
  float acc0 = 0.f, acc1 = 0.f;
  #pragma unroll 4
  for (int s=0; s<SRC; ++s){
    float al = als[s];
    acc0 += al * ew[(size_t)s*HID + tid];
    acc1 += al * ew[(size_t)s*HID + 512 + tid];
  }
  comb_a[b*HID + tid] = acc0;
  comb_a[b*HID + 512 + tid] = acc1;
}

// ===================== O = tanh(sum_kc partial_c + comb_a) ; write Obuf + out[t] =====================
__global__ void final_O_kernel(const float* __restrict__ partial_c, const float* __restrict__ comb_a,
                               float* __restrict__ Obuf, float* __restrict__ out, int t){
  int g = blockIdx.x*512 + threadIdx.x;   // 64*1024
  int n = g & 1023;
  int b = g >> 10;
  float s = comb_a[g];
  #pragma unroll
  for (int kc=0; kc<8; ++kc) s += partial_c[((size_t)(kc*64+b))*HID + n];
  float v = tanhf(s);
  Obuf[g] = v;
  out[(size_t)t*BATCH*HID + g] = v;
}

__global__ void zero_kernel(float* __restrict__ p, int n){
  int i = blockIdx.x*256 + threadIdx.x;
  if (i < n) p[i] = 0.f;
}

extern "C" void kernel_launch(void* const* d_in, const int* in_sizes, int n_in,
                              void* d_out, int out_size, void* d_ws, size_t ws_size,
                              hipStream_t stream) {
  const int*   tgt        = (const int*)d_in[0];
  const float* enc_hidden = (const float*)d_in[1];
  const int*   enc_mask   = (const int*)d_in[2];
  const float* dih        = (const float*)d_in[3];
  const float* dic        = (const float*)d_in[4];
  const float* emb        = (const float*)d_in[5];
  const float* W_ih       = (const float*)d_in[6];
  const float* W_hh       = (const float*)d_in[7];
  const float* b_ih       = (const float*)d_in[8];
  const float* b_hh       = (const float*)d_in[9];
  const float* W_att      = (const float*)d_in[10];
  const float* W_comb     = (const float*)d_in[11];
  float* out = (float*)d_out;

  float* ws        = (float*)d_ws;
  float* enc_proj  = ws;                          // 8192*1024
  float* encW      = enc_proj + 8388608;          // 8192*1024
  float* partial_g = encW + 8388608;              // 8*64*4096
  float* partial_c = partial_g + 2097152;         // 8*64*1024
  float* hh_term   = partial_c + 524288;          // 64*4096
  float* hbuf      = hh_term + 262144;            // 64*1024
  float* comb_a    = hbuf + 65536;                // 64*1024
  float* Obuf      = comb_a + 65536;              // 64*1024

  // ---- precompute ----
  // enc_proj[b*128+s][h] = enc_hidden[b,s,:] . W_att[h,:]   (M=8192,N=1024,K=2048)
  big_gemm<<<dim3(8,128), 256, 0, stream>>>(enc_hidden, 2048, W_att, 2048, enc_proj, HID, 2048);
  // encW[b*128+s][n] = enc_hidden[b,s,:] . W_comb[n, 1024:3072]
  big_gemm<<<dim3(8,128), 256, 0, stream>>>(enc_hidden, 2048, W_comb + HID, 3072, encW, HID, 2048);
  // hh_term = dih @ W_hh.T + b_ih + b_hh  (split-K partials then reduce)
  skinny_gemm<0><<<dim3(32,8), 256, 0, stream>>>(dih, HID, nullptr, nullptr, W_hh, HID, partial_g, G4, 128);
  hh_reduce_kernel<<<dim3(512), 512, 0, stream>>>(partial_g, b_ih, b_hh, hh_term);
  zero_kernel<<<dim3(256), 256, 0, stream>>>(Obuf, BATCH*HID);

  // ---- 64 decode steps ----
  for (int t = 0; t < NT; ++t){
    // gates partials: ybar=[emb[tok] | O_prev] @ W_ih.T   (K=1536, 8 chunks of 192)
    skinny_gemm<1><<<dim3(32,8), 256, 0, stream>>>(Obuf, HID, tgt + t*BATCH, emb, W_ih, 1536, partial_g, G4, 192);
    h_kernel<<<dim3(256), 256, 0, stream>>>(partial_g, hh_term, dic, hbuf);
    // comb h-part partials: h @ W_comb[:, :1024].T   (K=1024, 8 chunks of 128)
    skinny_gemm<0><<<dim3(8,8), 256, 0, stream>>>(hbuf, HID, nullptr, nullptr, W_comb, 3072, partial_c, HID, 128);
    attn_kernel<<<dim3(64), 512, 0, stream>>>(hbuf, enc_proj, encW, enc_mask, comb_a);
    final_O_kernel<<<dim3(128), 512, 0, stream>>>(partial_c, comb_a, Obuf, out, t);
  }
}

// Round 3
// 5166.101 us; speedup vs baseline: 4.8560x; 1.0455x over previous
//
#include <hip/hip_runtime.h>
#include <hip/hip_bf16.h>
#include <math.h>

// Decoder with attention: V=32000 E=512 H=1024 B=64 S=128 T=65 (NT=64 steps)
#define BATCH 64
#define SRC   128
#define HID   1024
#define EMB   512
#define NT    64
#define G4    4096   // 4H

__device__ __forceinline__ float sigmoidf_(float x){ return 1.0f/(1.0f+expf(-x)); }

// ===================== skinny GEMM: partial[kc][m][n] = sum_k A[m][k]*W[n][k] =====================
// M=64 (batch), BN=128, BK=16, split-K via blockIdx.y. 256 threads = 4 waves.
// wave owns 64x32 sub-tile; micro 8(m)x4(n).
// AMODE 0: A[m][k] with leading dim lda.
// AMODE 1: k<512 -> emb[toks[m]][k], else A[m][k-512].
template<int AMODE>
__launch_bounds__(256, 2)
__global__ void skinny_gemm(const float* __restrict__ A, int lda,
                            const int* __restrict__ toks, const float* __restrict__ emb,
                            const float* __restrict__ W, int ldw,
                            float* __restrict__ partial, int N, int Kchunk){
  const int nc = blockIdx.x;
  const int kc = blockIdx.y;
  const int kbase = kc * Kchunk;
  const int tid = threadIdx.x;
  __shared__ float As[16][68];
  __shared__ float Bs[16][132];
  const int wave = tid >> 6, lane = tid & 63;
  const int lm = lane & 7, ln = lane >> 3;
  const int nwave = nc*128 + wave*32;
  float acc[8][4] = {};
  const int arow = tid >> 2, akc = (tid & 3) * 4;
  for (int k0 = 0; k0 < Kchunk; k0 += 16){
    int kg = kbase + k0 + akc;
    float4 av;
    if (AMODE == 1){
      if (kg < EMB) av = *(const float4*)(emb + (size_t)toks[arow]*EMB + kg);
      else          av = *(const float4*)(A + (size_t)arow*lda + (kg - EMB));
    } else {
      av = *(const float4*)(A + (size_t)arow*lda + kg);
    }
    As[akc+0][arow]=av.x; As[akc+1][arow]=av.y; As[akc+2][arow]=av.z; As[akc+3][arow]=av.w;
    #pragma unroll
    for (int r = 0; r < 2; ++r){
      int idx = tid + r*256;
      int nrow = idx >> 2, bkc = (idx & 3) * 4;
      float4 wv = *(const float4*)(W + (size_t)(nc*128 + nrow)*ldw + kbase + k0 + bkc);
      Bs[bkc+0][nrow]=wv.x; Bs[bkc+1][nrow]=wv.y; Bs[bkc+2][nrow]=wv.z; Bs[bkc+3][nrow]=wv.w;
    }
    __syncthreads();
    #pragma unroll
    for (int k = 0; k < 16; ++k){
      float4 alo = *(const float4*)&As[k][lm*8];
      float4 ahi = *(const float4*)&As[k][lm*8+4];
      float4 b4  = *(const float4*)&Bs[k][wave*32 + ln*4];
      float am[8] = {alo.x,alo.y,alo.z,alo.w,ahi.x,ahi.y,ahi.z,ahi.w};
      float bn[4] = {b4.x,b4.y,b4.z,b4.w};
      #pragma unroll
      for (int i=0;i<8;++i)
        #pragma unroll
        for (int j=0;j<4;++j)
          acc[i][j] += am[i]*bn[j];
    }
    __syncthreads();
  }
  for (int i=0;i<8;++i){
    int m = lm*8+i;
    float4 v = make_float4(acc[i][0],acc[i][1],acc[i][2],acc[i][3]);
    *(float4*)(partial + ((size_t)(kc*64 + m))*N + nwave + ln*4) = v;
  }
}

// ===================== big GEMM 128x128, 8x8 micro: C[m][n] = sum_k A[m][k]*W[n][k] ============
// 256 threads = 4 waves, wave grid 2(m)x2(n), wave tile 64x64, lane micro 8x8.
__launch_bounds__(256, 2)
__global__ void big_gemm128(const float* __restrict__ A, int lda,
                            const float* __restrict__ W, int ldw,
                            float* __restrict__ C, int N, int K){
  const int n0 = blockIdx.x * 128;
  const int m0 = blockIdx.y * 128;
  const int tid = threadIdx.x;
  __shared__ float As[16][132];
  __shared__ float Bs[16][132];
  const int wave = tid >> 6, lane = tid & 63;
  const int wm = wave >> 1, wn = wave & 1;
  const int lm = lane & 7, ln = lane >> 3;
  float acc[8][8] = {};
  for (int k0 = 0; k0 < K; k0 += 16){
    #pragma unroll
    for (int r = 0; r < 2; ++r){
      int idx = tid + r*256;
      int row = idx >> 2, kq = (idx & 3) * 4;
      float4 av = *(const float4*)(A + (size_t)(m0+row)*lda + k0 + kq);
      As[kq+0][row]=av.x; As[kq+1][row]=av.y; As[kq+2][row]=av.z; As[kq+3][row]=av.w;
      float4 wv = *(const float4*)(W + (size_t)(n0+row)*ldw + k0 + kq);
      Bs[kq+0][row]=wv.x; Bs[kq+1][row]=wv.y; Bs[kq+2][row]=wv.z; Bs[kq+3][row]=wv.w;
    }
    __syncthreads();
    #pragma unroll
    for (int k = 0; k < 16; ++k){
      float4 a0 = *(const float4*)&As[k][wm*64 + lm*8];
      float4 a1 = *(const float4*)&As[k][wm*64 + lm*8 + 4];
      float4 b0 = *(const float4*)&Bs[k][wn*64 + ln*8];
      float4 b1 = *(const float4*)&Bs[k][wn*64 + ln*8 + 4];
      float am[8] = {a0.x,a0.y,a0.z,a0.w,a1.x,a1.y,a1.z,a1.w};
      float bn[8] = {b0.x,b0.y,b0.z,b0.w,b1.x,b1.y,b1.z,b1.w};
      #pragma unroll
      for (int i=0;i<8;++i)
        #pragma unroll
        for (int j=0;j<8;++j)
          acc[i][j] += am[i]*bn[j];
    }
    __syncthreads();
  }
  for (int i=0;i<8;++i){
    int m = m0 + wm*64 + lm*8 + i;
    float* cp = C + (size_t)m*N + n0 + wn*64 + ln*8;
    *(float4*)cp     = make_float4(acc[i][0],acc[i][1],acc[i][2],acc[i][3]);
    *(float4*)(cp+4) = make_float4(acc[i][4],acc[i][5],acc[i][6],acc[i][7]);
  }
}

// ===================== hh_term = sum_kc partial + b_ih + b_hh =====================
__global__ void hh_reduce_kernel(const float* __restrict__ partial,
                                 const float* __restrict__ b_ih, const float* __restrict__ b_hh,
                                 float* __restrict__ hh_term){
  int g = blockIdx.x*512 + threadIdx.x;   // 64*4096
  int n = g & 4095;
  int b = g >> 12;
  float s = b_ih[n] + b_hh[n];
  #pragma unroll
  for (int kc=0; kc<8; ++kc) s += partial[((size_t)(kc*64+b))*G4 + n];
  hh_term[g] = s;
}

// ===================== h chunk (LSTM nonlin) + e partial over chunk =====================
// grid (64 b, 4 chunk), 256 threads. e_part[b][ch][s] = sum_{j in chunk} enc_proj[b][s][j]*h[j]
__global__ void h_e_kernel(const float* __restrict__ partial_g, const float* __restrict__ hh_term,
                           const float* __restrict__ c0, const float* __restrict__ enc_proj,
                           float* __restrict__ hbuf, float* __restrict__ e_part){
  const int b = blockIdx.x, ch = blockIdx.y;
  const int tid = threadIdx.x;
  __shared__ float hs[256];
  const int j = ch*256 + tid;
  float gate[4];
  #pragma unroll
  for (int q=0;q<4;++q){
    int n = q*HID + j;
    float s = hh_term[b*G4 + n];
    #pragma unroll
    for (int kc=0;kc<8;++kc) s += partial_g[((size_t)(kc*64+b))*G4 + n];
    gate[q]=s;
  }
  float c = sigmoidf_(gate[1])*c0[b*HID+j] + sigmoidf_(gate[0])*tanhf(gate[2]);
  float h = sigmoidf_(gate[3])*tanhf(c);
  hs[tid] = h;
  hbuf[b*HID + j] = h;
  __syncthreads();
  const int wave = tid>>6, lane = tid&63;
  float4 hv = *(const float4*)&hs[lane*4];
  for (int s = wave; s < SRC; s += 4){
    const float* ep = enc_proj + ((size_t)b*SRC + s)*HID + ch*256;
    float4 v = *(const float4*)(ep + lane*4);
    float sum = v.x*hv.x + v.y*hv.y + v.z*hv.z + v.w*hv.w;
    #pragma unroll
    for (int off=32; off; off>>=1) sum += __shfl_down(sum, off);
    if (lane==0) e_part[(b*4 + ch)*SRC + s] = sum;
  }
}

// ===================== e reduce + softmax + comb_a + comb_h reduce + tanh + write ==============
// grid (64 b, 4 nchunk), 256 threads.
__global__ void soft_comb_kernel(const float* __restrict__ e_part, const int* __restrict__ enc_mask,
                                 const float* __restrict__ encW, const float* __restrict__ partial_c,
                                 float* __restrict__ Obuf, float* __restrict__ out, int t){
  const int b = blockIdx.x, ch = blockIdx.y;
  const int tid = threadIdx.x;
  __shared__ float als[SRC];
  __shared__ float red[SRC];
  float ev = 0.f; bool msk = false;
  if (tid < SRC){
    ev = e_part[(b*4+0)*SRC+tid] + e_part[(b*4+1)*SRC+tid]
       + e_part[(b*4+2)*SRC+tid] + e_part[(b*4+3)*SRC+tid];
    msk = (enc_mask[b*SRC+tid] != 0);
    red[tid] = msk ? -1e30f : ev;
  }
  __syncthreads();
  for (int off=64; off>=1; off>>=1){ if (tid<off) red[tid]=fmaxf(red[tid],red[tid+off]); __syncthreads(); }
  float mval = red[0]; __syncthreads();
  float p = (tid<SRC && !msk) ? expf(ev-mval) : 0.f;
  if (tid<SRC) red[tid]=p;
  __syncthreads();
  for (int off=64; off>=1; off>>=1){ if (tid<off) red[tid]+=red[tid+off]; __syncthreads(); }
  if (tid<SRC) als[tid] = p/red[0];
  __syncthreads();
  const int j = ch*256 + tid;
  const float* ew = encW + (size_t)b*SRC*HID + j;
  float acc = 0.f;
  #pragma unroll 8
  for (int s=0;s<SRC;++s) acc += als[s]*ew[(size_t)s*HID];
  #pragma unroll
  for (int kc=0;kc<16;++kc) acc += partial_c[((size_t)(kc*64+b))*HID + j];
  float v = tanhf(acc);
  Obuf[b*HID+j] = v;
  out[(size_t)t*BATCH*HID + b*HID + j] = v;
}

__global__ void zero_kernel(float* __restrict__ p, int n){
  int i = blockIdx.x*256 + threadIdx.x;
  if (i < n) p[i] = 0.f;
}

extern "C" void kernel_launch(void* const* d_in, const int* in_sizes, int n_in,
                              void* d_out, int out_size, void* d_ws, size_t ws_size,
                              hipStream_t stream) {
  const int*   tgt        = (const int*)d_in[0];
  const float* enc_hidden = (const float*)d_in[1];
  const int*   enc_mask   = (const int*)d_in[2];
  const float* dih        = (const float*)d_in[3];
  const float* dic        = (const float*)d_in[4];
  const float* emb        = (const float*)d_in[5];
  const float* W_ih       = (const float*)d_in[6];
  const float* W_hh       = (const float*)d_in[7];
  const float* b_ih       = (const float*)d_in[8];
  const float* b_hh       = (const float*)d_in[9];
  const float* W_att      = (const float*)d_in[10];
  const float* W_comb     = (const float*)d_in[11];
  float* out = (float*)d_out;

  float* ws        = (float*)d_ws;
  float* enc_proj  = ws;                          // 8192*1024
  float* encW      = enc_proj + 8388608;          // 8192*1024
  float* partial_g = encW + 8388608;              // 8*64*4096
  float* partial_c = partial_g + 2097152;         // 16*64*1024
  float* hh_term   = partial_c + 1048576;         // 64*4096
  float* hbuf      = hh_term + 262144;            // 64*1024
  float* e_part    = hbuf + 65536;                // 64*4*128
  float* Obuf      = e_part + 32768;              // 64*1024

  // ---- precompute ----
  // enc_proj[b*128+s][h] = enc_hidden[b,s,:] . W_att[h,:]   (M=8192,N=1024,K=2048)
  big_gemm128<<<dim3(8,64), 256, 0, stream>>>(enc_hidden, 2048, W_att, 2048, enc_proj, HID, 2048);
  // encW[b*128+s][n] = enc_hidden[b,s,:] . W_comb[n, 1024:3072]
  big_gemm128<<<dim3(8,64), 256, 0, stream>>>(enc_hidden, 2048, W_comb + HID, 3072, encW, HID, 2048);
  // hh_term = dih @ W_hh.T + b_ih + b_hh
  skinny_gemm<0><<<dim3(32,8), 256, 0, stream>>>(dih, HID, nullptr, nullptr, W_hh, HID, partial_g, G4, 128);
  hh_reduce_kernel<<<dim3(512), 512, 0, stream>>>(partial_g, b_ih, b_hh, hh_term);
  zero_kernel<<<dim3(256), 256, 0, stream>>>(Obuf, BATCH*HID);

  // ---- 64 decode steps ----
  for (int t = 0; t < NT; ++t){
    // gates partials: ybar=[emb[tok] | O_prev] @ W_ih.T  (K=1536, 8 chunks of 192)
    skinny_gemm<1><<<dim3(32,8), 256, 0, stream>>>(Obuf, HID, tgt + t*BATCH, emb, W_ih, 1536, partial_g, G4, 192);
    // h + e partials (256 blocks)
    h_e_kernel<<<dim3(64,4), 256, 0, stream>>>(partial_g, hh_term, dic, enc_proj, hbuf, e_part);
    // comb h-part partials: h @ W_comb[:, :1024].T  (K=1024, 16 chunks of 64)
    skinny_gemm<0><<<dim3(8,16), 256, 0, stream>>>(hbuf, HID, nullptr, nullptr, W_comb, 3072, partial_c, HID, 64);
    // softmax + comb_a + comb_h reduce + tanh + write (256 blocks)
    soft_comb_kernel<<<dim3(64,4), 256, 0, stream>>>(e_part, enc_mask, encW, partial_c, Obuf, out, t);
  }
}